// Round 4
// baseline (276.118 us; speedup 1.0000x reference)
//
#include <hip/hip_runtime.h>

#define LOG2E 1.4426950408889634f

// Problem constants
constexpr int Bb = 4, LQ = 512, LK = 512, QS = 512, H = 256, DV = 512;
constexpr int M = Bb * LQ;   // 2048 rows for both projections

// ---------------------------------------------------------------------------
// Kernel A: fused Q/K projection + exp2 epilogue, TRANSPOSED output.
//   EqT[n][m] = exp2( clamp( scale*(A[m]·W[n] + bias[n]), ±60 ) )
// 1024-thread blocks (16 waves/CU even at 1 block/CU — rocprof shows the HW
// only keeps ~1 block/CU resident here).  64m x 64n tile, 2x2/thread,
// dot-product form: As/Ws staged row-major [row][k] pitch 36 (144B = 16B
// aligned; b128 frag reads lane-stride 36 floats are octet-conflict-free,
// measured 0 conflicts in r3).  Grid (32, 4, 2) = 256 blocks.
// ---------------------------------------------------------------------------
__global__ __launch_bounds__(1024) void proj2_kernel(
    const float* __restrict__ Aq, const float* __restrict__ Ak,
    const float* __restrict__ Wq, const float* __restrict__ Wk,
    const float* __restrict__ Bq, const float* __restrict__ Bk,
    float* __restrict__ EqT, float* __restrict__ EkT, float scale)
{
    const int K = QS;
    const float* A    = blockIdx.z ? Ak : Aq;
    const float* W    = blockIdx.z ? Wk : Wq;
    const float* bias = blockIdx.z ? Bk : Bq;
    float*       C    = blockIdx.z ? EkT : EqT;   // [H][M] transposed

    __shared__ float As[64][36];   // [m][k]
    __shared__ float Ws[64][36];   // [n][k]
    const int bm = blockIdx.x * 64;
    const int bn = blockIdx.y * 64;
    const int tid = threadIdx.x;
    const int tx = tid & 31;       // m: tx, tx+32  (contiguous output dim)
    const int ty = tid >> 5;       // n: ty, ty+32

    float4 accv[2][2] = {};        // component-wise partial sums (k mod 4)

    const int sr = (tid & 511) >> 3;     // 0..63 staging row
    const int sc = (tid & 7) * 4;        // 0..28 staging col
    const bool stageW = tid >= 512;
    const float* gsrc = stageW ? W : A;
    const int gro = stageW ? bn : bm;
    float* ldst = stageW ? &Ws[0][0] : &As[0][0];

    for (int k0 = 0; k0 < K; k0 += 32) {
        *(float4*)(ldst + sr * 36 + sc) =
            *(const float4*)(gsrc + (size_t)(gro + sr) * K + k0 + sc);
        __syncthreads();
#pragma unroll
        for (int kk = 0; kk < 8; ++kk) {
            const float4 a0 = *(const float4*)&As[tx][kk * 4];
            const float4 a1 = *(const float4*)&As[tx + 32][kk * 4];
            const float4 w0 = *(const float4*)&Ws[ty][kk * 4];
            const float4 w1 = *(const float4*)&Ws[ty + 32][kk * 4];
            accv[0][0].x = fmaf(a0.x, w0.x, accv[0][0].x);
            accv[0][0].y = fmaf(a0.y, w0.y, accv[0][0].y);
            accv[0][0].z = fmaf(a0.z, w0.z, accv[0][0].z);
            accv[0][0].w = fmaf(a0.w, w0.w, accv[0][0].w);
            accv[0][1].x = fmaf(a0.x, w1.x, accv[0][1].x);
            accv[0][1].y = fmaf(a0.y, w1.y, accv[0][1].y);
            accv[0][1].z = fmaf(a0.z, w1.z, accv[0][1].z);
            accv[0][1].w = fmaf(a0.w, w1.w, accv[0][1].w);
            accv[1][0].x = fmaf(a1.x, w0.x, accv[1][0].x);
            accv[1][0].y = fmaf(a1.y, w0.y, accv[1][0].y);
            accv[1][0].z = fmaf(a1.z, w0.z, accv[1][0].z);
            accv[1][0].w = fmaf(a1.w, w0.w, accv[1][0].w);
            accv[1][1].x = fmaf(a1.x, w1.x, accv[1][1].x);
            accv[1][1].y = fmaf(a1.y, w1.y, accv[1][1].y);
            accv[1][1].z = fmaf(a1.z, w1.z, accv[1][1].z);
            accv[1][1].w = fmaf(a1.w, w1.w, accv[1][1].w);
        }
        __syncthreads();
    }
    // Epilogue: horizontal sum, bias, scale, clamp, exp2, transposed store.
    // Store C[n][bm+tx+32i]: lanes tx contiguous -> coalesced per row.
#pragma unroll
    for (int j = 0; j < 2; ++j) {
        int n = bn + ty + 32 * j;
        float bs = bias[n];
#pragma unroll
        for (int i = 0; i < 2; ++i) {
            float4 s4 = accv[i][j];
            float s = (s4.x + s4.y) + (s4.z + s4.w);
            float v = scale * (s + bs);
            v = fminf(fmaxf(v, -60.f), 60.f);
            C[(size_t)n * M + bm + tx + 32 * i] = __builtin_amdgcn_exp2f(v);
        }
    }
}

// ---------------------------------------------------------------------------
// Kernel B: scores (log2 domain, bv dropped).
//   s' = SW - sum_h Wv2[h] * rcp(1 + EqT[h][q]*EkT[h][k])
// 1024-thread blocks, 64q x 64k tile, 2x2/thread, grid (8,8,B) = 256 blocks.
// Staging contiguous row-major (conflict-free).  Frag reads: Qs b64 2-addr
// broadcast, Ks b64 stride-2 (2-way, free).
// ---------------------------------------------------------------------------
__global__ __launch_bounds__(1024) void score_kernel(
    const float* __restrict__ EqT,   // [H][M] exp2 domain
    const float* __restrict__ EkT,   // [H][M]
    const float* __restrict__ wv,    // [H]
    float* __restrict__ Sc)          // [B*LQ, LK]
{
    __shared__ float Qs[32][64];
    __shared__ float Ks[32][64];
    __shared__ float Wv2[H];
    const int b  = blockIdx.z;
    const int qb = blockIdx.x * 64, kb = blockIdx.y * 64;
    const int tid = threadIdx.x;
    const int tx = tid & 31;       // k pair: kb + tx*2 + j
    const int ty = tid >> 5;       // q pair: qb + ty*2 + i

    if (tid < H) Wv2[tid] = wv[tid] * (2.0f * LOG2E);
    __syncthreads();

    float SW;
    {
        float4 s4 = {0.f, 0.f, 0.f, 0.f};
        for (int h = 0; h < H; h += 4) {
            float4 w4 = *(const float4*)&Wv2[h];
            s4.x += w4.x; s4.y += w4.y; s4.z += w4.z; s4.w += w4.w;
        }
        SW = 0.5f * ((s4.x + s4.y) + (s4.z + s4.w));
    }

    float acc[2][2] = {};
    const int mq = b * LQ + qb;
    const int mk = b * LK + kb;
    const int sh = (tid & 511) >> 4;   // 0..31 staging row (h)
    const int sm = (tid & 15) * 4;     // 0..60 staging col (m)
    const bool stageK = tid >= 512;
    const float* src = stageK ? EkT : EqT;
    const int mo = stageK ? mk : mq;
    float* dst = stageK ? &Ks[0][0] : &Qs[0][0];

    for (int h0 = 0; h0 < H; h0 += 32) {
        *(float4*)(dst + sh * 64 + sm) =
            *(const float4*)(src + (size_t)(h0 + sh) * M + mo + sm);
        __syncthreads();
#pragma unroll
        for (int h = 0; h < 32; ++h) {
            float w = Wv2[h0 + h];
            float2 q2 = *(const float2*)&Qs[h][ty * 2];
            float2 k2 = *(const float2*)&Ks[h][tx * 2];
            float t00 = fmaf(q2.x, k2.x, 1.0f);
            float t01 = fmaf(q2.x, k2.y, 1.0f);
            float t10 = fmaf(q2.y, k2.x, 1.0f);
            float t11 = fmaf(q2.y, k2.y, 1.0f);
            acc[0][0] = fmaf(w, __builtin_amdgcn_rcpf(t00), acc[0][0]);
            acc[0][1] = fmaf(w, __builtin_amdgcn_rcpf(t01), acc[0][1]);
            acc[1][0] = fmaf(w, __builtin_amdgcn_rcpf(t10), acc[1][0]);
            acc[1][1] = fmaf(w, __builtin_amdgcn_rcpf(t11), acc[1][1]);
        }
        __syncthreads();
    }
#pragma unroll
    for (int i = 0; i < 2; ++i) {
        int q = qb + ty * 2 + i;
        float2 o;
        o.x = SW - acc[i][0];
        o.y = SW - acc[i][1];
        *(float2*)(Sc + ((size_t)b * LQ + q) * LK + kb + tx * 2) = o;
    }
}

// ---------------------------------------------------------------------------
// Kernel C: row softmax in-place on Sc (log2 domain -> plain exp2).
// One block (256 thr) per row of 512; 2 elements/thread.
// ---------------------------------------------------------------------------
__global__ __launch_bounds__(256) void softmax_kernel(float* __restrict__ Sc)
{
    const int row = blockIdx.x;
    float* s = Sc + (size_t)row * LK;
    const int tid = threadIdx.x;
    float2 v = *(float2*)(s + tid * 2);

    float m = fmaxf(v.x, v.y);
#pragma unroll
    for (int off = 32; off >= 1; off >>= 1)
        m = fmaxf(m, __shfl_xor(m, off, 64));
    __shared__ float redm[4];
    const int wid = tid >> 6, lane = tid & 63;
    if (lane == 0) redm[wid] = m;
    __syncthreads();
    m = fmaxf(fmaxf(redm[0], redm[1]), fmaxf(redm[2], redm[3]));

    float e0 = __builtin_amdgcn_exp2f(v.x - m);
    float e1 = __builtin_amdgcn_exp2f(v.y - m);
    float sum = e0 + e1;
#pragma unroll
    for (int off = 32; off >= 1; off >>= 1)
        sum += __shfl_xor(sum, off, 64);
    __shared__ float reds[4];
    if (lane == 0) reds[wid] = sum;
    __syncthreads();
    sum = (reds[0] + reds[1]) + (reds[2] + reds[3]);

    float rs = 1.0f / sum;
    float2 o; o.x = e0 * rs; o.y = e1 * rs;
    *(float2*)(s + tid * 2) = o;
}

// ---------------------------------------------------------------------------
// Kernel D: out = attn @ value.  O[q][n] = sum_k At[q][k] * V[k][n].
// 1024-thread blocks, 64q x 64n tile, 2x2/thread, grid (8,8,B) = 256 blocks.
// At staged [q][k] pitch 36 (b128 reads, ~broadcast); V staged [k][n]
// natural (b64 stride-2 reads, 2-way free).
// ---------------------------------------------------------------------------
__global__ __launch_bounds__(1024) void av_kernel(
    const float* __restrict__ At,   // [B*LQ, LK] attention weights
    const float* __restrict__ V,    // [B, LK, DV]
    float* __restrict__ O)          // [B*LQ, DV]
{
    __shared__ float As[64][36];    // [q][k]
    __shared__ float Vs[32][64];    // [k][n]
    const int b  = blockIdx.z;
    const int qb = blockIdx.x * 64, nb = blockIdx.y * 64;
    const int tid = threadIdx.x;
    const int tx = tid & 31;        // n pair: nb + tx*2 + j
    const int ty = tid >> 5;        // q pair: qb + ty*2 + i
    float acc[2][2] = {};
    const float* Ab = At + ((size_t)b * LQ + qb) * LK;
    const float* Vb = V + (size_t)b * LK * DV;

    const int ar = (tid & 511) >> 3;   // 0..63
    const int ac = (tid & 7) * 4;      // 0..28
    const int vr = (tid & 511) >> 4;   // 0..31
    const int vc = (tid & 15) * 4;     // 0..60
    const bool stageV = tid >= 512;

    for (int k0 = 0; k0 < LK; k0 += 32) {
        if (!stageV) {
            *(float4*)&As[ar][ac] =
                *(const float4*)(Ab + (size_t)ar * LK + k0 + ac);
        } else {
            *(float4*)&Vs[vr][vc] =
                *(const float4*)(Vb + (size_t)(k0 + vr) * DV + nb + vc);
        }
        __syncthreads();
#pragma unroll
        for (int k4 = 0; k4 < 8; ++k4) {
            const float4 a0 = *(const float4*)&As[ty * 2 + 0][k4 * 4];
            const float4 a1 = *(const float4*)&As[ty * 2 + 1][k4 * 4];
            const float2 v0 = *(const float2*)&Vs[k4 * 4 + 0][tx * 2];
            const float2 v1 = *(const float2*)&Vs[k4 * 4 + 1][tx * 2];
            const float2 v2 = *(const float2*)&Vs[k4 * 4 + 2][tx * 2];
            const float2 v3 = *(const float2*)&Vs[k4 * 4 + 3][tx * 2];
            acc[0][0] = fmaf(a0.x, v0.x, acc[0][0]);
            acc[0][1] = fmaf(a0.x, v0.y, acc[0][1]);
            acc[1][0] = fmaf(a1.x, v0.x, acc[1][0]);
            acc[1][1] = fmaf(a1.x, v0.y, acc[1][1]);
            acc[0][0] = fmaf(a0.y, v1.x, acc[0][0]);
            acc[0][1] = fmaf(a0.y, v1.y, acc[0][1]);
            acc[1][0] = fmaf(a1.y, v1.x, acc[1][0]);
            acc[1][1] = fmaf(a1.y, v1.y, acc[1][1]);
            acc[0][0] = fmaf(a0.z, v2.x, acc[0][0]);
            acc[0][1] = fmaf(a0.z, v2.y, acc[0][1]);
            acc[1][0] = fmaf(a1.z, v2.x, acc[1][0]);
            acc[1][1] = fmaf(a1.z, v2.y, acc[1][1]);
            acc[0][0] = fmaf(a0.w, v3.x, acc[0][0]);
            acc[0][1] = fmaf(a0.w, v3.y, acc[0][1]);
            acc[1][0] = fmaf(a1.w, v3.x, acc[1][0]);
            acc[1][1] = fmaf(a1.w, v3.y, acc[1][1]);
        }
        __syncthreads();
    }
#pragma unroll
    for (int i = 0; i < 2; ++i) {
        int q = qb + ty * 2 + i;
        float2 o;
        o.x = acc[i][0];
        o.y = acc[i][1];
        *(float2*)(O + ((size_t)b * LQ + q) * DV + nb + tx * 2) = o;
    }
}

extern "C" void kernel_launch(void* const* d_in, const int* in_sizes, int n_in,
                              void* d_out, int out_size, void* d_ws, size_t ws_size,
                              hipStream_t stream) {
    const float* query = (const float*)d_in[0];
    const float* key   = (const float*)d_in[1];
    const float* value = (const float*)d_in[2];
    const float* wq    = (const float*)d_in[3];
    const float* bq    = (const float*)d_in[4];
    const float* wk    = (const float*)d_in[5];
    const float* bk    = (const float*)d_in[6];
    const float* wv    = (const float*)d_in[7];
    // d_in[8] = bv: row-constant -> softmax-invariant, dropped.
    float* out = (float*)d_out;

    float* EqT = (float*)d_ws;                     // [H][M] exp2-domain q
    float* EkT = EqT + (size_t)H * M;              // [H][M] exp2-domain k
    float* Sc  = EkT + (size_t)H * M;              // [M][LK] scores/attn

    const float c2 = 2.0f * LOG2E;

    proj2_kernel<<<dim3(M / 64, H / 64, 2), 1024, 0, stream>>>(
        query, key, wq, wk, bq, bk, EqT, EkT, c2);
    score_kernel<<<dim3(LQ / 64, LK / 64, Bb), 1024, 0, stream>>>(EqT, EkT, wv, Sc);
    softmax_kernel<<<Bb * LQ, 256, 0, stream>>>(Sc);
    av_kernel<<<dim3(LQ / 64, DV / 64, Bb), 1024, 0, stream>>>(Sc, value, out);
}

// Round 5
// 215.368 us; speedup vs baseline: 1.2821x; 1.2821x over previous
//
#include <hip/hip_runtime.h>

#define LOG2E 1.4426950408889634f

// Problem constants
constexpr int Bb = 4, LQ = 512, LK = 512, QS = 512, H = 256, DV = 512;
constexpr int M = Bb * LQ;   // 2048 rows for both projections

// ---------------------------------------------------------------------------
// Kernel A: fused Q/K projection + exp2 epilogue, TRANSPOSED output.
//   EqT[n][m] = exp2( clamp( scale*(A[m]·W[n] + bias[n]), ±60 ) )
// 256 thr, 64m x 64n tile, 4x4/thread, dot-product over k (BK=32).
// Staging row-major pitch 36 (R3's measured-0-conflict layout; b128 frag
// reads lane-stride 36 floats = 4 banks -> 2-way, free).  Register prefetch
// overlaps next chunk's global loads with compute.  Grid (32,4,2) = 256 blk.
// ---------------------------------------------------------------------------
__global__ __launch_bounds__(256) void proj2_kernel(
    const float* __restrict__ Aq, const float* __restrict__ Ak,
    const float* __restrict__ Wq, const float* __restrict__ Wk,
    const float* __restrict__ Bq, const float* __restrict__ Bk,
    float* __restrict__ EqT, float* __restrict__ EkT, float scale)
{
    const int K = QS;
    const float* A    = blockIdx.z ? Ak : Aq;
    const float* W    = blockIdx.z ? Wk : Wq;
    const float* bias = blockIdx.z ? Bk : Bq;
    float*       C    = blockIdx.z ? EkT : EqT;   // [H][M] transposed

    __shared__ float As[64][36];   // [m][k]
    __shared__ float Ws[64][36];   // [n][k]
    const int bm = blockIdx.x * 64;
    const int bn = blockIdx.y * 64;
    const int tid = threadIdx.x;
    const int tx = tid & 15;       // m frag: tx + 16*i
    const int ty = tid >> 4;       // n frag: ty + 16*j

    const int sr = tid >> 3;           // staging row 0..31 (+32 on it=1)
    const int sc = (tid & 7) * 4;      // staging col 0..28

    float acc[4][4] = {};
    float4 pa[2], pw[2];

    // prefetch chunk 0
#pragma unroll
    for (int it = 0; it < 2; ++it) {
        pa[it] = *(const float4*)(A + (size_t)(bm + sr + 32 * it) * K + sc);
        pw[it] = *(const float4*)(W + (size_t)(bn + sr + 32 * it) * K + sc);
    }

    for (int k0 = 0; k0 < K; k0 += 32) {
        __syncthreads();
#pragma unroll
        for (int it = 0; it < 2; ++it) {
            *(float4*)&As[sr + 32 * it][sc] = pa[it];
            *(float4*)&Ws[sr + 32 * it][sc] = pw[it];
        }
        __syncthreads();
        if (k0 + 32 < K) {
#pragma unroll
            for (int it = 0; it < 2; ++it) {
                pa[it] = *(const float4*)(A + (size_t)(bm + sr + 32 * it) * K + k0 + 32 + sc);
                pw[it] = *(const float4*)(W + (size_t)(bn + sr + 32 * it) * K + k0 + 32 + sc);
            }
        }
#pragma unroll
        for (int kk = 0; kk < 8; ++kk) {
            float4 a[4], w[4];
#pragma unroll
            for (int i = 0; i < 4; ++i) a[i] = *(const float4*)&As[tx + 16 * i][kk * 4];
#pragma unroll
            for (int j = 0; j < 4; ++j) w[j] = *(const float4*)&Ws[ty + 16 * j][kk * 4];
#pragma unroll
            for (int i = 0; i < 4; ++i)
#pragma unroll
                for (int j = 0; j < 4; ++j) {
                    acc[i][j] = fmaf(a[i].x, w[j].x, acc[i][j]);
                    acc[i][j] = fmaf(a[i].y, w[j].y, acc[i][j]);
                    acc[i][j] = fmaf(a[i].z, w[j].z, acc[i][j]);
                    acc[i][j] = fmaf(a[i].w, w[j].w, acc[i][j]);
                }
        }
    }
    // Epilogue: bias, scale, clamp, exp2, transposed store (lanes tx give
    // 16 contiguous floats per segment).
#pragma unroll
    for (int j = 0; j < 4; ++j) {
        int n = bn + ty + 16 * j;
        float bs = bias[n];
#pragma unroll
        for (int i = 0; i < 4; ++i) {
            float v = scale * (acc[i][j] + bs);
            v = fminf(fmaxf(v, -60.f), 60.f);
            C[(size_t)n * M + bm + tx + 16 * i] = __builtin_amdgcn_exp2f(v);
        }
    }
}

// ---------------------------------------------------------------------------
// Kernel B: scores (log2 domain, bv dropped), TRANSPOSED output ScT[k][q].
//   s'(q,k) = SW - sum_h Wv2[h] * rcp(1 + EqT[h][q]*EkT[h][k])
// 256 thr, 64q x 64k tile, 4x4/thread (16 independent rcp chains per h),
// h-chunk 32, register prefetch.  Staging contiguous row-major [h][m]
// (conflict-free float4 writes); q-frag b128 lane-stride 4 banks (free),
// k-frag b128 broadcast.  Grid (8,8,B) = 256 blocks.
// ---------------------------------------------------------------------------
__global__ __launch_bounds__(256) void score_kernel(
    const float* __restrict__ EqT,   // [H][M] exp2 domain
    const float* __restrict__ EkT,   // [H][M]
    const float* __restrict__ wv,    // [H]
    float* __restrict__ ScT)         // [B][LK][LQ]  (k-major!)
{
    __shared__ float Qs[32][64];
    __shared__ float Ks[32][64];
    __shared__ float Wv2[H];
    const int b  = blockIdx.z;
    const int qb = blockIdx.x * 64, kb = blockIdx.y * 64;
    const int tid = threadIdx.x;
    const int tx = tid & 15;       // q frag: tx*4 + i
    const int ty = tid >> 4;       // k frag: ty*4 + j

    Wv2[tid] = wv[tid] * (2.0f * LOG2E);   // blockDim == H == 256
    __syncthreads();

    float SW;
    {
        float4 s4 = {0.f, 0.f, 0.f, 0.f};
        for (int h = 0; h < H; h += 4) {
            float4 w4 = *(const float4*)&Wv2[h];
            s4.x += w4.x; s4.y += w4.y; s4.z += w4.z; s4.w += w4.w;
        }
        SW = 0.5f * ((s4.x + s4.y) + (s4.z + s4.w));
    }

    float acc[4][4] = {};
    const int mq = b * LQ + qb;
    const int mk = b * LK + kb;
    const int sh = tid >> 4;           // staging row 0..15 (+16 on it=1)
    const int sm = (tid & 15) * 4;     // staging col 0..60

    float4 pq[2], pk[2];
#pragma unroll
    for (int it = 0; it < 2; ++it) {
        pq[it] = *(const float4*)(EqT + (size_t)(sh + 16 * it) * M + mq + sm);
        pk[it] = *(const float4*)(EkT + (size_t)(sh + 16 * it) * M + mk + sm);
    }

    for (int h0 = 0; h0 < H; h0 += 32) {
        __syncthreads();
#pragma unroll
        for (int it = 0; it < 2; ++it) {
            *(float4*)&Qs[sh + 16 * it][sm] = pq[it];
            *(float4*)&Ks[sh + 16 * it][sm] = pk[it];
        }
        __syncthreads();
        if (h0 + 32 < H) {
#pragma unroll
            for (int it = 0; it < 2; ++it) {
                pq[it] = *(const float4*)(EqT + (size_t)(h0 + 32 + sh + 16 * it) * M + mq + sm);
                pk[it] = *(const float4*)(EkT + (size_t)(h0 + 32 + sh + 16 * it) * M + mk + sm);
            }
        }
#pragma unroll 4
        for (int h = 0; h < 32; ++h) {
            const float4 q4 = *(const float4*)&Qs[h][tx * 4];
            const float4 k4 = *(const float4*)&Ks[h][ty * 4];
            const float w = Wv2[h0 + h];
            const float qa[4] = {q4.x, q4.y, q4.z, q4.w};
            const float ka[4] = {k4.x, k4.y, k4.z, k4.w};
#pragma unroll
            for (int i = 0; i < 4; ++i)
#pragma unroll
                for (int j = 0; j < 4; ++j) {
                    float t = fmaf(qa[i], ka[j], 1.0f);   // >= 1, rcp safe
                    acc[i][j] = fmaf(w, __builtin_amdgcn_rcpf(t), acc[i][j]);
                }
        }
    }
    // Transposed store: ScT[b][k][q], q contiguous -> b128, 16 lanes x 16B.
#pragma unroll
    for (int j = 0; j < 4; ++j) {
        int k = kb + ty * 4 + j;
        float4 o;
        o.x = SW - acc[0][j];
        o.y = SW - acc[1][j];
        o.z = SW - acc[2][j];
        o.w = SW - acc[3][j];
        *(float4*)(ScT + ((size_t)b * LK + k) * LQ + qb + tx * 4) = o;
    }
}

// ---------------------------------------------------------------------------
// Kernel C: fused softmax + (attn @ V).
// Phase 1: per-q-row max and sum of exp2 over all 512 k, streaming ScT
// columns (lanes cover 64 contiguous q -> coalesced; L2/L3-warm).
// Phase 2: k-chunks of 32: stage P = exp2(s - rowmax) straight from ScT
// (contiguous float4, conflict-free) + V tile; 4x4 outer-product GEMM;
// epilogue scales by 1/rowsum.  Grid (8,8,B) = 256 blocks, 256 thr.
// ---------------------------------------------------------------------------
__global__ __launch_bounds__(256) void av_fused_kernel(
    const float* __restrict__ ScT,  // [B][LK][LQ]
    const float* __restrict__ V,    // [B][LK][DV]
    float* __restrict__ O)          // [B][LQ][DV]
{
    __shared__ float Ps[32][64];    // [k][q] probabilities (unnormalized)
    __shared__ float Vs[32][64];    // [k][n]
    __shared__ float red[4][64];
    __shared__ float rowmax[64];
    __shared__ float rowrcp[64];

    const int b  = blockIdx.z;
    const int qb = blockIdx.x * 64, nb = blockIdx.y * 64;
    const int tid = threadIdx.x;
    const float* S  = ScT + (size_t)b * LK * LQ;
    const float* Vb = V + (size_t)b * LK * DV;

    // ---- phase 1: row stats over all k ----
    const int ql = tid & 63;        // local q
    const int st = tid >> 6;        // k stripe 0..3 (128 k each)
    const float* cp = S + qb + ql;

    float m = -1e30f;
#pragma unroll 8
    for (int kk = st * 128; kk < st * 128 + 128; ++kk)
        m = fmaxf(m, cp[(size_t)kk * LQ]);
    red[st][ql] = m;
    __syncthreads();
    float rm = fmaxf(fmaxf(red[0][ql], red[1][ql]), fmaxf(red[2][ql], red[3][ql]));
    __syncthreads();   // red reuse guard

    float s = 0.f;
#pragma unroll 8
    for (int kk = st * 128; kk < st * 128 + 128; ++kk)
        s += __builtin_amdgcn_exp2f(cp[(size_t)kk * LQ] - rm);
    red[st][ql] = s;
    if (st == 0) rowmax[ql] = rm;
    __syncthreads();
    if (st == 0) {
        float sum = ((red[0][ql] + red[1][ql]) + (red[2][ql] + red[3][ql]));
        rowrcp[ql] = 1.0f / sum;
    }
    // (sync happens at top of the k-loop below)

    // ---- phase 2: GEMM over k chunks ----
    const int tx = tid & 15;        // q frag: tx*4 + i
    const int ty = tid >> 4;        // n frag: ty*4 + j
    const int sr = tid >> 4;        // staging row 0..15 (+16)
    const int sc = (tid & 15) * 4;  // staging col 0..60
    float acc[4][4] = {};

    float4 pp[2], pv[2];
#pragma unroll
    for (int it = 0; it < 2; ++it) {
        pp[it] = *(const float4*)(S + (size_t)(sr + 16 * it) * LQ + qb + sc);
        pv[it] = *(const float4*)(Vb + (size_t)(sr + 16 * it) * DV + nb + sc);
    }

    for (int k0 = 0; k0 < LK; k0 += 32) {
        __syncthreads();
#pragma unroll
        for (int it = 0; it < 2; ++it) {
            float4 p = pp[it];
            p.x = __builtin_amdgcn_exp2f(p.x - rowmax[sc + 0]);
            p.y = __builtin_amdgcn_exp2f(p.y - rowmax[sc + 1]);
            p.z = __builtin_amdgcn_exp2f(p.z - rowmax[sc + 2]);
            p.w = __builtin_amdgcn_exp2f(p.w - rowmax[sc + 3]);
            *(float4*)&Ps[sr + 16 * it][sc] = p;
            *(float4*)&Vs[sr + 16 * it][sc] = pv[it];
        }
        __syncthreads();
        if (k0 + 32 < LK) {
#pragma unroll
            for (int it = 0; it < 2; ++it) {
                pp[it] = *(const float4*)(S + (size_t)(k0 + 32 + sr + 16 * it) * LQ + qb + sc);
                pv[it] = *(const float4*)(Vb + (size_t)(k0 + 32 + sr + 16 * it) * DV + nb + sc);
            }
        }
#pragma unroll 8
        for (int k = 0; k < 32; ++k) {
            const float4 p4 = *(const float4*)&Ps[k][tx * 4];
            const float4 v4 = *(const float4*)&Vs[k][ty * 4];
            const float pa[4] = {p4.x, p4.y, p4.z, p4.w};
            const float va[4] = {v4.x, v4.y, v4.z, v4.w};
#pragma unroll
            for (int i = 0; i < 4; ++i)
#pragma unroll
                for (int j = 0; j < 4; ++j)
                    acc[i][j] = fmaf(pa[i], va[j], acc[i][j]);
        }
    }
    // Epilogue: normalize and store.
#pragma unroll
    for (int i = 0; i < 4; ++i) {
        int q = qb + tx * 4 + i;
        float rr = rowrcp[tx * 4 + i];
        float4 o;
        o.x = acc[i][0] * rr;
        o.y = acc[i][1] * rr;
        o.z = acc[i][2] * rr;
        o.w = acc[i][3] * rr;
        *(float4*)(O + ((size_t)b * LQ + q) * DV + nb + ty * 4) = o;
    }
}

extern "C" void kernel_launch(void* const* d_in, const int* in_sizes, int n_in,
                              void* d_out, int out_size, void* d_ws, size_t ws_size,
                              hipStream_t stream) {
    const float* query = (const float*)d_in[0];
    const float* key   = (const float*)d_in[1];
    const float* value = (const float*)d_in[2];
    const float* wq    = (const float*)d_in[3];
    const float* bq    = (const float*)d_in[4];
    const float* wk    = (const float*)d_in[5];
    const float* bk    = (const float*)d_in[6];
    const float* wv    = (const float*)d_in[7];
    // d_in[8] = bv: row-constant -> softmax-invariant, dropped.
    float* out = (float*)d_out;

    float* EqT = (float*)d_ws;                     // [H][M] exp2-domain q
    float* EkT = EqT + (size_t)H * M;              // [H][M] exp2-domain k
    float* ScT = EkT + (size_t)H * M;              // [B][LK][LQ] scores (k-major)

    const float c2 = 2.0f * LOG2E;

    proj2_kernel<<<dim3(M / 64, H / 64, 2), 256, 0, stream>>>(
        query, key, wq, wk, bq, bk, EqT, EkT, c2);
    score_kernel<<<dim3(LQ / 64, LK / 64, Bb), 256, 0, stream>>>(EqT, EkT, wv, ScT);
    av_fused_kernel<<<dim3(LQ / 64, DV / 64, Bb), 256, 0, stream>>>(ScT, value, out);
}

// Round 6
// 191.830 us; speedup vs baseline: 1.4394x; 1.1227x over previous
//
#include <hip/hip_runtime.h>

#define LOG2E 1.4426950408889634f

// Problem constants
constexpr int Bb = 4, LQ = 512, LK = 512, QS = 512, H = 256, DV = 512;
constexpr int M = Bb * LQ;   // 2048 rows for both projections

// ---------------------------------------------------------------------------
// Kernel A: fused Q/K projection + exp2 epilogue, TRANSPOSED output.
//   EqT[n][m] = exp2( clamp( scale*(A[m]·W[n] + bias[n]), ±30 ) )
// Clamp is ±30 so that downstream pair-products (1+EqEk)(1+EqEk) stay
// below 2^122 < fp32 max.  256 thr, 64x64 tile, 4x4/thread, BK=32,
// register prefetch, pitch-36 row-major staging (measured 0 conflicts).
// ---------------------------------------------------------------------------
__global__ __launch_bounds__(256) void proj2_kernel(
    const float* __restrict__ Aq, const float* __restrict__ Ak,
    const float* __restrict__ Wq, const float* __restrict__ Wk,
    const float* __restrict__ Bq, const float* __restrict__ Bk,
    float* __restrict__ EqT, float* __restrict__ EkT, float scale)
{
    const int K = QS;
    const float* A    = blockIdx.z ? Ak : Aq;
    const float* W    = blockIdx.z ? Wk : Wq;
    const float* bias = blockIdx.z ? Bk : Bq;
    float*       C    = blockIdx.z ? EkT : EqT;   // [H][M] transposed

    __shared__ float As[64][36];   // [m][k]
    __shared__ float Ws[64][36];   // [n][k]
    const int bm = blockIdx.x * 64;
    const int bn = blockIdx.y * 64;
    const int tid = threadIdx.x;
    const int tx = tid & 15;       // m frag: tx + 16*i
    const int ty = tid >> 4;       // n frag: ty + 16*j

    const int sr = tid >> 3;           // staging row 0..31 (+32 on it=1)
    const int sc = (tid & 7) * 4;      // staging col 0..28

    float acc[4][4] = {};
    float4 pa[2], pw[2];

#pragma unroll
    for (int it = 0; it < 2; ++it) {
        pa[it] = *(const float4*)(A + (size_t)(bm + sr + 32 * it) * K + sc);
        pw[it] = *(const float4*)(W + (size_t)(bn + sr + 32 * it) * K + sc);
    }

    for (int k0 = 0; k0 < K; k0 += 32) {
        __syncthreads();
#pragma unroll
        for (int it = 0; it < 2; ++it) {
            *(float4*)&As[sr + 32 * it][sc] = pa[it];
            *(float4*)&Ws[sr + 32 * it][sc] = pw[it];
        }
        __syncthreads();
        if (k0 + 32 < K) {
#pragma unroll
            for (int it = 0; it < 2; ++it) {
                pa[it] = *(const float4*)(A + (size_t)(bm + sr + 32 * it) * K + k0 + 32 + sc);
                pw[it] = *(const float4*)(W + (size_t)(bn + sr + 32 * it) * K + k0 + 32 + sc);
            }
        }
#pragma unroll
        for (int kk = 0; kk < 8; ++kk) {
            float4 a[4], w[4];
#pragma unroll
            for (int i = 0; i < 4; ++i) a[i] = *(const float4*)&As[tx + 16 * i][kk * 4];
#pragma unroll
            for (int j = 0; j < 4; ++j) w[j] = *(const float4*)&Ws[ty + 16 * j][kk * 4];
#pragma unroll
            for (int i = 0; i < 4; ++i)
#pragma unroll
                for (int j = 0; j < 4; ++j) {
                    acc[i][j] = fmaf(a[i].x, w[j].x, acc[i][j]);
                    acc[i][j] = fmaf(a[i].y, w[j].y, acc[i][j]);
                    acc[i][j] = fmaf(a[i].z, w[j].z, acc[i][j]);
                    acc[i][j] = fmaf(a[i].w, w[j].w, acc[i][j]);
                }
        }
    }
#pragma unroll
    for (int j = 0; j < 4; ++j) {
        int n = bn + ty + 16 * j;
        float bs = bias[n];
#pragma unroll
        for (int i = 0; i < 4; ++i) {
            float v = scale * (acc[i][j] + bs);
            v = fminf(fmaxf(v, -30.f), 30.f);
            C[(size_t)n * M + bm + tx + 16 * i] = __builtin_amdgcn_exp2f(v);
        }
    }
}

// ---------------------------------------------------------------------------
// Kernel B: scores -> unnormalized softmax numerators P, + row sums.
//   acc(q,k) = sum_h Wv2[h]/(1 + Eq[h][q]*Ek[h][k]);  P = exp2(-acc)
// (global shift SW and bv dropped — cancel in softmax; no max subtraction
// needed since |acc| <= sum|Wv2| ~ 46 and exp2(+-46) is fine in fp32).
// h-terms PAIRED: w1/t1 + w2/t2 = (w1*t2 + w2*t1)/(t1*t2) — one rcp per TWO
// elements (rcp is quarter-rate; this halves the trans-pipe load that R3/R5
// counters show is the saturated pipe).  Epilogue: store P into ScT[k][q]
// (b128) and atomicAdd per-q row sums.  Grid (8,8,B) = 256 blocks.
// ---------------------------------------------------------------------------
__global__ __launch_bounds__(256) void score_kernel(
    const float* __restrict__ EqT,   // [H][M] exp2 domain
    const float* __restrict__ EkT,   // [H][M]
    const float* __restrict__ wv,    // [H]
    float* __restrict__ ScT,         // [B][LK][LQ]  (k-major)
    float* __restrict__ rowsum)      // [B*LQ], pre-zeroed
{
    __shared__ float Qs[32][64];
    __shared__ float Ks[32][64];
    __shared__ float Wv2[H];
    __shared__ float red[16][64];
    const int b  = blockIdx.z;
    const int qb = blockIdx.x * 64, kb = blockIdx.y * 64;
    const int tid = threadIdx.x;
    const int tx = tid & 15;       // q frag: tx*4 + i
    const int ty = tid >> 4;       // k frag: ty*4 + j

    Wv2[tid] = wv[tid] * (2.0f * LOG2E);   // blockDim == H == 256
    __syncthreads();

    float acc[4][4] = {};
    const int mq = b * LQ + qb;
    const int mk = b * LK + kb;
    const int sh = tid >> 4;           // staging row 0..15 (+16 on it=1)
    const int sm = (tid & 15) * 4;     // staging col 0..60

    float4 pq[2], pk[2];
#pragma unroll
    for (int it = 0; it < 2; ++it) {
        pq[it] = *(const float4*)(EqT + (size_t)(sh + 16 * it) * M + mq + sm);
        pk[it] = *(const float4*)(EkT + (size_t)(sh + 16 * it) * M + mk + sm);
    }

    for (int h0 = 0; h0 < H; h0 += 32) {
        __syncthreads();
#pragma unroll
        for (int it = 0; it < 2; ++it) {
            *(float4*)&Qs[sh + 16 * it][sm] = pq[it];
            *(float4*)&Ks[sh + 16 * it][sm] = pk[it];
        }
        __syncthreads();
        if (h0 + 32 < H) {
#pragma unroll
            for (int it = 0; it < 2; ++it) {
                pq[it] = *(const float4*)(EqT + (size_t)(h0 + 32 + sh + 16 * it) * M + mq + sm);
                pk[it] = *(const float4*)(EkT + (size_t)(h0 + 32 + sh + 16 * it) * M + mk + sm);
            }
        }
#pragma unroll
        for (int h = 0; h < 32; h += 2) {
            const float4 q1 = *(const float4*)&Qs[h][tx * 4];
            const float4 q2 = *(const float4*)&Qs[h + 1][tx * 4];
            const float4 k1 = *(const float4*)&Ks[h][ty * 4];
            const float4 k2 = *(const float4*)&Ks[h + 1][ty * 4];
            const float w1 = Wv2[h0 + h];
            const float w2 = Wv2[h0 + h + 1];
            const float q1a[4] = {q1.x, q1.y, q1.z, q1.w};
            const float q2a[4] = {q2.x, q2.y, q2.z, q2.w};
            const float k1a[4] = {k1.x, k1.y, k1.z, k1.w};
            const float k2a[4] = {k2.x, k2.y, k2.z, k2.w};
#pragma unroll
            for (int i = 0; i < 4; ++i)
#pragma unroll
                for (int j = 0; j < 4; ++j) {
                    float ta = fmaf(q1a[i], k1a[j], 1.0f);
                    float tb = fmaf(q2a[i], k2a[j], 1.0f);
                    float num = fmaf(w1, tb, w2 * ta);
                    float den = ta * tb;
                    acc[i][j] = fmaf(num, __builtin_amdgcn_rcpf(den), acc[i][j]);
                }
        }
    }

    // Epilogue: P = exp2(-acc), store transposed, accumulate row partials.
    float ps[4] = {0.f, 0.f, 0.f, 0.f};
#pragma unroll
    for (int j = 0; j < 4; ++j) {
        int k = kb + ty * 4 + j;
        float4 o;
        o.x = __builtin_amdgcn_exp2f(-acc[0][j]); ps[0] += o.x;
        o.y = __builtin_amdgcn_exp2f(-acc[1][j]); ps[1] += o.y;
        o.z = __builtin_amdgcn_exp2f(-acc[2][j]); ps[2] += o.z;
        o.w = __builtin_amdgcn_exp2f(-acc[3][j]); ps[3] += o.w;
        *(float4*)(ScT + ((size_t)b * LK + k) * LQ + qb + tx * 4) = o;
    }
#pragma unroll
    for (int i = 0; i < 4; ++i) red[ty][tx * 4 + i] = ps[i];
    __syncthreads();
    if (tid < 64) {
        float s = 0.f;
#pragma unroll
        for (int r = 0; r < 16; ++r) s += red[r][tid];
        atomicAdd(&rowsum[b * LQ + qb + tid], s);
    }
}

// ---------------------------------------------------------------------------
// Kernel C: out = (P @ V) * (1/rowsum).  Pure prefetched fp32 GEMM.
// 256 thr, 64q x 64n tile, 4x4/thread, BK=32.  Grid (8,8,B) = 256 blocks.
// ---------------------------------------------------------------------------
__global__ __launch_bounds__(256) void av_kernel(
    const float* __restrict__ ScT,  // [B][LK][LQ]  P values
    const float* __restrict__ V,    // [B][LK][DV]
    const float* __restrict__ rowsum, // [B*LQ]
    float* __restrict__ O)          // [B][LQ][DV]
{
    __shared__ float Ps[32][64];    // [k][q]
    __shared__ float Vs[32][64];    // [k][n]
    const int b  = blockIdx.z;
    const int qb = blockIdx.x * 64, nb = blockIdx.y * 64;
    const int tid = threadIdx.x;
    const int tx = tid & 15;        // q frag: tx*4 + i
    const int ty = tid >> 4;        // n frag: ty*4 + j
    const float* S  = ScT + (size_t)b * LK * LQ;
    const float* Vb = V + (size_t)b * LK * DV;

    const int sr = tid >> 4;        // staging row 0..15 (+16)
    const int sc = (tid & 15) * 4;  // staging col 0..60
    float acc[4][4] = {};

    float4 pp[2], pv[2];
#pragma unroll
    for (int it = 0; it < 2; ++it) {
        pp[it] = *(const float4*)(S + (size_t)(sr + 16 * it) * LQ + qb + sc);
        pv[it] = *(const float4*)(Vb + (size_t)(sr + 16 * it) * DV + nb + sc);
    }

    for (int k0 = 0; k0 < LK; k0 += 32) {
        __syncthreads();
#pragma unroll
        for (int it = 0; it < 2; ++it) {
            *(float4*)&Ps[sr + 16 * it][sc] = pp[it];
            *(float4*)&Vs[sr + 16 * it][sc] = pv[it];
        }
        __syncthreads();
        if (k0 + 32 < LK) {
#pragma unroll
            for (int it = 0; it < 2; ++it) {
                pp[it] = *(const float4*)(S + (size_t)(k0 + 32 + sr + 16 * it) * LQ + qb + sc);
                pv[it] = *(const float4*)(Vb + (size_t)(k0 + 32 + sr + 16 * it) * DV + nb + sc);
            }
        }
#pragma unroll
        for (int k = 0; k < 32; ++k) {
            const float4 p4 = *(const float4*)&Ps[k][tx * 4];
            const float4 v4 = *(const float4*)&Vs[k][ty * 4];
            const float pa[4] = {p4.x, p4.y, p4.z, p4.w};
            const float va[4] = {v4.x, v4.y, v4.z, v4.w};
#pragma unroll
            for (int i = 0; i < 4; ++i)
#pragma unroll
                for (int j = 0; j < 4; ++j)
                    acc[i][j] = fmaf(pa[i], va[j], acc[i][j]);
        }
    }
    // Epilogue: normalize by 1/rowsum and store.
#pragma unroll
    for (int i = 0; i < 4; ++i) {
        int q = qb + tx * 4 + i;
        float rr = 1.0f / rowsum[b * LQ + q];
        float4 o;
        o.x = acc[i][0] * rr;
        o.y = acc[i][1] * rr;
        o.z = acc[i][2] * rr;
        o.w = acc[i][3] * rr;
        *(float4*)(O + ((size_t)b * LQ + q) * DV + nb + ty * 4) = o;
    }
}

extern "C" void kernel_launch(void* const* d_in, const int* in_sizes, int n_in,
                              void* d_out, int out_size, void* d_ws, size_t ws_size,
                              hipStream_t stream) {
    const float* query = (const float*)d_in[0];
    const float* key   = (const float*)d_in[1];
    const float* value = (const float*)d_in[2];
    const float* wq    = (const float*)d_in[3];
    const float* bq    = (const float*)d_in[4];
    const float* wk    = (const float*)d_in[5];
    const float* bk    = (const float*)d_in[6];
    const float* wv    = (const float*)d_in[7];
    // d_in[8] = bv: row-constant -> softmax-invariant, dropped.
    float* out = (float*)d_out;

    float* EqT = (float*)d_ws;                     // [H][M]
    float* EkT = EqT + (size_t)H * M;              // [H][M]
    float* ScT = EkT + (size_t)H * M;              // [B][LK][LQ] P values
    float* rowsum = ScT + (size_t)Bb * LK * LQ;    // [B*LQ]

    const float c2 = 2.0f * LOG2E;

    hipMemsetAsync(rowsum, 0, (size_t)M * sizeof(float), stream);
    proj2_kernel<<<dim3(M / 64, H / 64, 2), 256, 0, stream>>>(
        query, key, wq, wk, bq, bk, EqT, EkT, c2);
    score_kernel<<<dim3(LQ / 64, LK / 64, Bb), 256, 0, stream>>>(
        EqT, EkT, wv, ScT, rowsum);
    av_kernel<<<dim3(LQ / 64, DV / 64, Bb), 256, 0, stream>>>(
        ScT, value, rowsum, out);
}